// Round 13
// baseline (845.949 us; speedup 1.0000x reference)
//
#include <hip/hip_runtime.h>
#include <hip/hip_bf16.h>

// WindowAttentionV2: B_NW=2048, N=64, DIM=512, NH=16, DH=32, HID=384, NW=64
// v11: convert_x FUSED into qkv (A reg-staged fp32->bf16, issue-early, swizzled ds_write;
//      B via global_load_lds with pre-swizzled source). 128^2 tiles everywhere (v9 geometry).
//      attn / proj / comb unchanged from v9 (751.5 us build).

typedef __bf16 bf16;
typedef __bf16 v4bf __attribute__((ext_vector_type(4)));
typedef __bf16 v8bf __attribute__((ext_vector_type(8)));
typedef float  v4f  __attribute__((ext_vector_type(4)));

// swizzle: involution on 8KB tile (128 rows x 64B); flips bits 4-6 by bits 7-9.
__device__ __forceinline__ int swz(int o) { return o ^ (((o >> 7) & 7) << 4); }

// ---------------- K0: weights -> transposed bf16 ----------------
__global__ void convert_w_kernel(const float* __restrict__ wqkv, const float* __restrict__ wout,
                                 bf16* __restrict__ Wt, bf16* __restrict__ WoT) {
    int idx = blockIdx.x * 256 + threadIdx.x;        // 786,432 threads
    Wt[idx] = (bf16)wqkv[(idx & 511) * 1536 + (idx >> 9)];
    if (idx < 262144) WoT[idx] = (bf16)wout[(idx & 511) * 512 + (idx >> 9)];
}

// ---------------- K1a: meta-MLP bias[h][i][j] ----------------
__global__ void bias_kernel(const float* __restrict__ rel_log, const float* __restrict__ w1,
                            const float* __restrict__ b1, const float* __restrict__ w2,
                            const float* __restrict__ b2, float* __restrict__ bias) {
    int p = blockIdx.x * 256 + threadIdx.x;          // (i,j) pair, 4096 total
    float ra = rel_log[p * 2 + 0];
    float rb = rel_log[p * 2 + 1];
    float acc[16];
    #pragma unroll
    for (int t = 0; t < 16; ++t) acc[t] = 0.f;
    for (int kk = 0; kk < 384; ++kk) {
        float hv = fmaxf(ra * w1[kk] + rb * w1[384 + kk] + b1[kk], 0.f);
        #pragma unroll
        for (int t = 0; t < 16; ++t) acc[t] += hv * w2[kk * 16 + t];
    }
    #pragma unroll
    for (int t = 0; t < 16; ++t) bias[t * 4096 + p] = acc[t] + b2[t];
}

// ---------------- K1b: comb swizzled for the SWAPPED (S^T) frag layout ----------------
__global__ void comb_kernel(const float* __restrict__ bias, const float* __restrict__ mask,
                            float* __restrict__ comb) {
    int idx = blockIdx.x * 256 + threadIdx.x;        // 4,194,304 threads (16384 blocks)
    int t = idx & 4095, wh = idx >> 12;
    int w = wh >> 4, h = wh & 15;
    int ji = t >> 8, rem = t & 255;
    int j = ji >> 2, i = ji & 3;
    int q16 = rem >> 2, r = t & 3;
    int lq = q16 >> 4, lm = q16 & 15;
    int p = (i * 16 + lm) * 64 + j * 16 + lq * 4 + r;
    comb[idx] = bias[h * 4096 + p] + mask[w * 4096 + p];
}

// ---------------- K2: qkv GEMM, fp32-A fused convert, swizzled LDS, 2-phase ----------------
// Tile 128x128, BK=32, 4 waves. Grid 12288 blocks (1024 m-tiles x 12 nb); nb fastest after swizzle.
// Outputs (UNNORMALIZED): q_ws/k_ws [bw*16+h][n][dh] bf16, v_ws [bw*16+h][dh][n] bf16.
__global__ __launch_bounds__(256) void qkv_gemm_kernel(
    const float* __restrict__ x,    // [131072][512] fp32 (read directly; convert fused)
    const bf16* __restrict__ Wt,    // [1536][512]
    bf16* __restrict__ q_ws, bf16* __restrict__ k_ws, bf16* __restrict__ v_ws)
{
    __shared__ alignas(16) char Alds[2][8192];      // 128 x 32 bf16, swizzled
    __shared__ alignas(16) char Blds[2][8192];
    const int bid = blockIdx.x, nwg = gridDim.x;
    const int wid = (bid & 7) * (nwg >> 3) + (bid >> 3);   // XCD-bijective (nwg%8==0)
    const int nb = wid % 12, mb = wid / 12;                // mb in [0, 1024)

    const int t = threadIdx.x;
    const int wv = t >> 6, lane = t & 63, lq = lane >> 4, lm = lane & 15;
    const int wr = wv >> 1, wc = wv & 1;

    // A staging: thread covers row srow, fp32 cols scol..scol+15 of the 32-col K-slice
    const int srow = t >> 1, scol = (t & 1) * 16;
    const float* aptr = x + (size_t)(mb * 128 + srow) * 512 + scol;
    const int wbyte = srow * 64 + scol * 2;          // byte offset of thread's 32B span
    const int wo0 = swz(wbyte), wo1 = swz(wbyte + 16);

    // B staging via gload_lds with pre-swizzled global source (v10-verified pattern)
    const char* bBase = (const char*)Wt + (size_t)(nb * 128) * 1024;
    int so[2], brow[2], bcol[2];
    #pragma unroll
    for (int p = 0; p < 2; ++p) {
        so[p] = p * 4096 + t * 16;                   // linear LDS dest (wave-uniform + lane*16)
        int s = swz(so[p]);
        brow[p] = s >> 6; bcol[p] = s & 63;
    }
    auto stageB = [&](int buf, int kt) {
        #pragma unroll
        for (int p = 0; p < 2; ++p)
            __builtin_amdgcn_global_load_lds(
                (const __attribute__((address_space(1))) void*)(bBase + (size_t)brow[p] * 1024 + kt * 64 + bcol[p]),
                (__attribute__((address_space(3))) void*)(&Blds[buf][0] + so[p]),
                16, 0, 0);
    };
    auto writeA = [&](int buf, float4 f0, float4 f1, float4 f2, float4 f3) {
        v8bf a0 = { (bf16)f0.x, (bf16)f0.y, (bf16)f0.z, (bf16)f0.w,
                    (bf16)f1.x, (bf16)f1.y, (bf16)f1.z, (bf16)f1.w };
        v8bf a1 = { (bf16)f2.x, (bf16)f2.y, (bf16)f2.z, (bf16)f2.w,
                    (bf16)f3.x, (bf16)f3.y, (bf16)f3.z, (bf16)f3.w };
        *(v8bf*)(&Alds[buf][0] + wo0) = a0;
        *(v8bf*)(&Alds[buf][0] + wo1) = a1;
    };

    // swizzled read offsets
    int aoff[4], boff[4];
    #pragma unroll
    for (int i = 0; i < 4; ++i) {
        aoff[i] = swz((wr * 64 + i * 16 + lm) * 64 + lq * 16);
        boff[i] = swz((wc * 64 + i * 16 + lm) * 64 + lq * 16);
    }

    v4f acc[4][4];
    #pragma unroll
    for (int i = 0; i < 4; ++i)
        #pragma unroll
        for (int j = 0; j < 4; ++j) acc[i][j] = v4f{0.f, 0.f, 0.f, 0.f};

    // prologue: tile 0
    {
        const float4* ap = (const float4*)aptr;
        float4 f0 = ap[0], f1 = ap[1], f2 = ap[2], f3 = ap[3];
        stageB(0, 0);
        writeA(0, f0, f1, f2, f3);
        __syncthreads();
    }

    #pragma unroll 1
    for (int kt = 0; kt < 16; ++kt) {
        const int cur = kt & 1;
        float4 f0, f1, f2, f3;
        if (kt < 15) {                               // issue-early: HBM latency hides under MFMA
            const float4* ap = (const float4*)(aptr + (kt + 1) * 32);
            f0 = ap[0]; f1 = ap[1]; f2 = ap[2]; f3 = ap[3];
            stageB(cur ^ 1, kt + 1);
        }
        v8bf af[4], bfj[4];
        #pragma unroll
        for (int i = 0; i < 4; ++i) af[i] = *(const v8bf*)(&Alds[cur][0] + aoff[i]);
        #pragma unroll
        for (int j = 0; j < 4; ++j) bfj[j] = *(const v8bf*)(&Blds[cur][0] + boff[j]);
        #pragma unroll
        for (int i = 0; i < 4; ++i)
            #pragma unroll
            for (int j = 0; j < 4; ++j)
                acc[i][j] = __builtin_amdgcn_mfma_f32_16x16x32_bf16(af[i], bfj[j], acc[i][j], 0, 0, 0);
        if (kt < 15) writeA(cur ^ 1, f0, f1, f2, f3);   // compiler inserts vmcnt before cvt
        __syncthreads();
    }

    // epilogue (v9-verified): row n = i*16+lq*4+r (window bw=mb*2+wr), col = nb*128+wc*64+j*16+lm
    const int bw = mb * 2 + wr;
    if (nb < 8) {
        bf16* dst = (nb < 4) ? q_ws : k_ws;
        const int hbase = (nb & 3) * 4 + wc * 2;
        #pragma unroll
        for (int tpair = 0; tpair < 2; ++tpair) {
            const int h = hbase + tpair;
            #pragma unroll
            for (int i = 0; i < 4; ++i)
                #pragma unroll
                for (int r = 0; r < 4; ++r) {
                    int n = i * 16 + lq * 4 + r;
                    size_t base = ((size_t)(bw * 16 + h) * 64 + n) * 32;
                    dst[base + lm]      = (bf16)acc[i][2 * tpair][r];
                    dst[base + 16 + lm] = (bf16)acc[i][2 * tpair + 1][r];
                }
        }
    } else {
        #pragma unroll
        for (int j = 0; j < 4; ++j) {
            const int h = (nb - 8) * 4 + wc * 2 + (j >> 1);
            const int dh = (j & 1) * 16 + lm;
            #pragma unroll
            for (int i = 0; i < 4; ++i) {
                v4bf pv = { (bf16)acc[i][j][0], (bf16)acc[i][j][1],
                            (bf16)acc[i][j][2], (bf16)acc[i][j][3] };
                *(v4bf*)(v_ws + ((size_t)(bw * 16 + h) * 32 + dh) * 64 + i * 16 + lq * 4) = pv;
            }
        }
    }
}

// ---------------- K3: attention, swapped QK^T, frag-local norm, 1 head/wave ----------------
__global__ __launch_bounds__(256) void attn_kernel(
    const bf16* __restrict__ q_ws,   // [bw*16+h][64][32] unnormalized
    const bf16* __restrict__ k_ws,
    const bf16* __restrict__ v_ws,   // [bw*16+h][32][64]
    const float* __restrict__ comb,  // [64][16][4096] swizzled for S^T frags
    const float* __restrict__ tau,   // [16]
    int wofs,
    bf16* __restrict__ attn_out)     // [rows][512]
{
    __shared__ alignas(16) bf16 P_all[4][64 * 72];
    const int blk = blockIdx.x;
    const int b = blk >> 2, g = blk & 3;
    const int tid = threadIdx.x;
    const int wv = tid >> 6, lane = tid & 63, lq = lane >> 4, lm = lane & 15;
    const int h = g * 4 + wv;
    const v4f z4 = {0.f, 0.f, 0.f, 0.f};

    bf16* P = P_all[wv];
    const size_t qk_base = (size_t)(b * 16 + h) * 64 * 32;
    const float* comb_hw = comb + ((size_t)(((wofs + b) & 63) * 16 + h)) * 4096
                                + (lq * 16 + lm) * 4;
    const float tau_h = tau[h];

    v8bf qf[4], kf[4];
    #pragma unroll
    for (int i = 0; i < 4; ++i)
        qf[i] = *(const v8bf*)(q_ws + qk_base + (i * 16 + lm) * 32 + lq * 8);
    #pragma unroll
    for (int j = 0; j < 4; ++j)
        kf[j] = *(const v8bf*)(k_ws + qk_base + (j * 16 + lm) * 32 + lq * 8);

    #pragma unroll
    for (int i = 0; i < 4; ++i) {
        float a = 0.f;
        #pragma unroll
        for (int e = 0; e < 8; ++e) { float f = (float)qf[i][e]; a = fmaf(f, f, a); }
        a += __shfl_xor(a, 16); a += __shfl_xor(a, 32);
        float sc = tau_h / fmaxf(sqrtf(a), 1e-12f);
        #pragma unroll
        for (int e = 0; e < 8; ++e) qf[i][e] = (bf16)((float)qf[i][e] * sc);
    }
    #pragma unroll
    for (int j = 0; j < 4; ++j) {
        float a = 0.f;
        #pragma unroll
        for (int e = 0; e < 8; ++e) { float f = (float)kf[j][e]; a = fmaf(f, f, a); }
        a += __shfl_xor(a, 16); a += __shfl_xor(a, 32);
        float sc = 1.0f / fmaxf(sqrtf(a), 1e-12f);
        #pragma unroll
        for (int e = 0; e < 8; ++e) kf[j][e] = (bf16)((float)kf[j][e] * sc);
    }

    v4f st[4][4];
    #pragma unroll
    for (int j = 0; j < 4; ++j)
        #pragma unroll
        for (int i = 0; i < 4; ++i)
            st[j][i] = __builtin_amdgcn_mfma_f32_16x16x32_bf16(kf[j], qf[i], z4, 0, 0, 0);

    #pragma unroll
    for (int j = 0; j < 4; ++j)
        #pragma unroll
        for (int i = 0; i < 4; ++i) {
            float4 cv = *(const float4*)(comb_hw + (j * 4 + i) * 256);
            st[j][i][0] += cv.x; st[j][i][1] += cv.y;
            st[j][i][2] += cv.z; st[j][i][3] += cv.w;
        }

    #pragma unroll
    for (int i = 0; i < 4; ++i) {
        float mx = st[0][i][0];
        #pragma unroll
        for (int j = 0; j < 4; ++j)
            #pragma unroll
            for (int r = 0; r < 4; ++r) mx = fmaxf(mx, st[j][i][r]);
        mx = fmaxf(mx, __shfl_xor(mx, 16));
        mx = fmaxf(mx, __shfl_xor(mx, 32));
        float sm = 0.f;
        #pragma unroll
        for (int j = 0; j < 4; ++j)
            #pragma unroll
            for (int r = 0; r < 4; ++r) {
                float e = __expf(st[j][i][r] - mx);
                st[j][i][r] = e; sm += e;
            }
        sm += __shfl_xor(sm, 16); sm += __shfl_xor(sm, 32);
        float rcp = 1.0f / sm;
        #pragma unroll
        for (int j = 0; j < 4; ++j) {
            v4bf pv = { (bf16)(st[j][i][0] * rcp), (bf16)(st[j][i][1] * rcp),
                        (bf16)(st[j][i][2] * rcp), (bf16)(st[j][i][3] * rcp) };
            *(v4bf*)(P + (i * 16 + lm) * 72 + j * 16 + lq * 4) = pv;
        }
    }

    const size_t v_base = (size_t)(b * 16 + h) * 32 * 64;
    v4f o[4][2];
    #pragma unroll
    for (int i = 0; i < 4; ++i)
        #pragma unroll
        for (int nt = 0; nt < 2; ++nt) o[i][nt] = z4;
    #pragma unroll
    for (int kk = 0; kk < 2; ++kk) {
        v8bf vf[2], pf[4];
        #pragma unroll
        for (int nt = 0; nt < 2; ++nt)
            vf[nt] = *(const v8bf*)(v_ws + v_base + (nt * 16 + lm) * 64 + kk * 32 + lq * 8);
        #pragma unroll
        for (int i = 0; i < 4; ++i)
            pf[i] = *(const v8bf*)(P + (i * 16 + lm) * 72 + kk * 32 + lq * 8);
        #pragma unroll
        for (int i = 0; i < 4; ++i)
            #pragma unroll
            for (int nt = 0; nt < 2; ++nt)
                o[i][nt] = __builtin_amdgcn_mfma_f32_16x16x32_bf16(pf[i], vf[nt], o[i][nt], 0, 0, 0);
    }
    #pragma unroll
    for (int i = 0; i < 4; ++i)
        #pragma unroll
        for (int nt = 0; nt < 2; ++nt)
            #pragma unroll
            for (int r = 0; r < 4; ++r)
                attn_out[(size_t)(b * 64 + i * 16 + lq * 4 + r) * 512 + h * 32 + nt * 16 + lm] =
                    (bf16)o[i][nt][r];
}

// ---------------- K4: out-projection GEMM, counted-vmcnt 2-buffer pipeline (v9) ----------------
__global__ __launch_bounds__(256) void proj_gemm_kernel(
    const bf16* __restrict__ A,     // [131072][512] attn_out
    const bf16* __restrict__ Bt,    // [512][512] WoT
    const float* __restrict__ b_out,
    float* __restrict__ out)        // [131072][512]
{
    __shared__ alignas(16) bf16 Alds[2][128 * 32];
    __shared__ alignas(16) bf16 Blds[2][128 * 32];
    const int bid = blockIdx.x;                       // 4096 blocks
    const int wid = (bid & 7) * 512 + (bid >> 3);     // XCD swizzle
    const int mb = wid >> 2, nb = wid & 3;            // nb fastest: A-tile reuse
    const int tid = threadIdx.x;
    const int wv = tid >> 6, lane = tid & 63, lq = lane >> 4, lm = lane & 15;
    const int wr = wv >> 1, wc = wv & 1;

    const char* aBase = (const char*)A + (size_t)mb * 128 * 1024;
    const char* bBase = (const char*)Bt + (size_t)nb * 128 * 1024;

    auto stage = [&](int buf, int kt) {
        #pragma unroll
        for (int p = 0; p < 2; ++p) {
            int idx = (p * 4 + wv) * 1024 + lane * 16;
            int row = idx >> 6, kb = idx & 63;
            __builtin_amdgcn_global_load_lds(
                (const __attribute__((address_space(1))) void*)(aBase + (size_t)row * 1024 + kt * 64 + kb),
                (__attribute__((address_space(3))) void*)((char*)Alds + buf * 8192 + (p * 4 + wv) * 1024),
                16, 0, 0);
            __builtin_amdgcn_global_load_lds(
                (const __attribute__((address_space(1))) void*)(bBase + (size_t)row * 1024 + kt * 64 + kb),
                (__attribute__((address_space(3))) void*)((char*)Blds + buf * 8192 + (p * 4 + wv) * 1024),
                16, 0, 0);
        }
    };

    v4f acc[4][4];
    #pragma unroll
    for (int i = 0; i < 4; ++i)
        #pragma unroll
        for (int j = 0; j < 4; ++j) acc[i][j] = v4f{0.f, 0.f, 0.f, 0.f};

    stage(0, 0);
    #pragma unroll 1
    for (int kt = 0; kt < 16; ++kt) {
        if (kt < 15) {
            stage((kt + 1) & 1, kt + 1);
            asm volatile("s_waitcnt vmcnt(4)" ::: "memory");
        } else {
            asm volatile("s_waitcnt vmcnt(0)" ::: "memory");
        }
        __builtin_amdgcn_s_barrier();
        __builtin_amdgcn_sched_barrier(0);
        const bf16* Ab = &Alds[kt & 1][0];
        const bf16* Bb = &Blds[kt & 1][0];
        v8bf af[4], bfj[4];
        #pragma unroll
        for (int i = 0; i < 4; ++i)
            af[i] = *(const v8bf*)(Ab + (wr * 64 + i * 16 + lm) * 32 + lq * 8);
        #pragma unroll
        for (int j = 0; j < 4; ++j)
            bfj[j] = *(const v8bf*)(Bb + (wc * 64 + j * 16 + lm) * 32 + lq * 8);
        #pragma unroll
        for (int i = 0; i < 4; ++i)
            #pragma unroll
            for (int j = 0; j < 4; ++j)
                acc[i][j] = __builtin_amdgcn_mfma_f32_16x16x32_bf16(af[i], bfj[j], acc[i][j], 0, 0, 0);
        __builtin_amdgcn_s_barrier();
    }

    #pragma unroll
    for (int j = 0; j < 4; ++j) {
        int col = nb * 128 + wc * 64 + j * 16 + lm;
        float bo = b_out[col];
        #pragma unroll
        for (int i = 0; i < 4; ++i)
            #pragma unroll
            for (int r = 0; r < 4; ++r)
                out[(size_t)(mb * 128 + wr * 64 + i * 16 + lq * 4 + r) * 512 + col] = acc[i][j][r] + bo;
    }
}

// ---------------- launch ----------------
extern "C" void kernel_launch(void* const* d_in, const int* in_sizes, int n_in,
                              void* d_out, int out_size, void* d_ws, size_t ws_size,
                              hipStream_t stream) {
    (void)in_sizes; (void)n_in; (void)out_size;
    const float* x       = (const float*)d_in[0];
    const float* mask    = (const float*)d_in[1];
    const float* w_qkv   = (const float*)d_in[2];
    const float* tau     = (const float*)d_in[3];
    const float* mlp_w1  = (const float*)d_in[4];
    const float* mlp_b1  = (const float*)d_in[5];
    const float* mlp_w2  = (const float*)d_in[6];
    const float* mlp_b2  = (const float*)d_in[7];
    const float* w_out   = (const float*)d_in[8];
    const float* b_out   = (const float*)d_in[9];
    const float* rel_log = (const float*)d_in[10];
    float* out = (float*)d_out;

    char* ws = (char*)d_ws;
    bf16*  Wt       = (bf16*)(ws);                   // 1,572,864 B
    bf16*  WoT      = (bf16*)(ws + 1572864);         //   524,288 B
    float* bias     = (float*)(ws + 2097152);        //   262,144 B
    float* comb     = (float*)(ws + 2359296);        //  16,777,216 B
    bf16*  attn_out = (bf16*)(ws + 19136512);        // 134,217,728 B
    char*  qkv_base = ws + 153354240;

    size_t avail = (ws_size > 153354240ULL) ? ws_size - 153354240ULL : 0;
    int W = 2048;                                    // 556 MB total; ws = 1 GiB (round-5 poison)
    while (W > 128 && (size_t)W * 196608ULL > avail) W >>= 1;
    const size_t qkbuf = (size_t)W * 65536;
    bf16* qb = (bf16*)qkv_base;
    bf16* kb = (bf16*)(qkv_base + qkbuf);
    bf16* vb = (bf16*)(qkv_base + 2 * qkbuf);

    convert_w_kernel<<<3072, 256, 0, stream>>>(w_qkv, w_out, Wt, WoT);
    bias_kernel<<<16, 256, 0, stream>>>(rel_log, mlp_w1, mlp_b1, mlp_w2, mlp_b2, bias);
    comb_kernel<<<16384, 256, 0, stream>>>(bias, mask, comb);

    const int nchunk = 2048 / W;
    for (int c = 0; c < nchunk; ++c) {
        const float* xc = x + (size_t)c * W * 64 * 512;
        bf16* aoc = attn_out + (size_t)c * W * 64 * 512;
        qkv_gemm_kernel<<<6 * W, 256, 0, stream>>>(xc, Wt, qb, kb, vb);
        attn_kernel<<<4 * W, 256, 0, stream>>>(qb, kb, vb, comb, tau, c * W, aoc);
    }
    proj_gemm_kernel<<<4096, 256, 0, stream>>>(attn_out, WoT, b_out, out);
}

// Round 14
// 753.660 us; speedup vs baseline: 1.1225x; 1.1225x over previous
//
#include <hip/hip_runtime.h>
#include <hip/hip_bf16.h>

// WindowAttentionV2: B_NW=2048, N=64, DIM=512, NH=16, DH=32, HID=384, NW=64
// v12: convert_x fused into qkv via ASYNC fp32-A staging (global_load_lds, counted vmcnt(6)),
//      convert at frag-read (ds_read_b128 x2 + cvt). A-tile swizzled (128B-row involution).
//      B-path / loop structure / attn / proj = v9 (751.5 us build).

typedef __bf16 bf16;
typedef __bf16 v4bf __attribute__((ext_vector_type(4)));
typedef __bf16 v8bf __attribute__((ext_vector_type(8)));
typedef float  v4f  __attribute__((ext_vector_type(4)));

// involution for fp32 A-tile (128 rows x 128 B): XOR row low bits into 16B-slot bits 4-6.
__device__ __forceinline__ int swz32(int o) { return o ^ (((o >> 7) & 7) << 4); }

// ---------------- K0: weights -> transposed bf16 ----------------
__global__ void convert_w_kernel(const float* __restrict__ wqkv, const float* __restrict__ wout,
                                 bf16* __restrict__ Wt, bf16* __restrict__ WoT) {
    int idx = blockIdx.x * 256 + threadIdx.x;        // 786,432 threads
    Wt[idx] = (bf16)wqkv[(idx & 511) * 1536 + (idx >> 9)];
    if (idx < 262144) WoT[idx] = (bf16)wout[(idx & 511) * 512 + (idx >> 9)];
}

// ---------------- K1a: meta-MLP bias[h][i][j] ----------------
__global__ void bias_kernel(const float* __restrict__ rel_log, const float* __restrict__ w1,
                            const float* __restrict__ b1, const float* __restrict__ w2,
                            const float* __restrict__ b2, float* __restrict__ bias) {
    int p = blockIdx.x * 256 + threadIdx.x;          // (i,j) pair, 4096 total
    float ra = rel_log[p * 2 + 0];
    float rb = rel_log[p * 2 + 1];
    float acc[16];
    #pragma unroll
    for (int t = 0; t < 16; ++t) acc[t] = 0.f;
    for (int kk = 0; kk < 384; ++kk) {
        float hv = fmaxf(ra * w1[kk] + rb * w1[384 + kk] + b1[kk], 0.f);
        #pragma unroll
        for (int t = 0; t < 16; ++t) acc[t] += hv * w2[kk * 16 + t];
    }
    #pragma unroll
    for (int t = 0; t < 16; ++t) bias[t * 4096 + p] = acc[t] + b2[t];
}

// ---------------- K1b: comb swizzled for the SWAPPED (S^T) frag layout ----------------
__global__ void comb_kernel(const float* __restrict__ bias, const float* __restrict__ mask,
                            float* __restrict__ comb) {
    int idx = blockIdx.x * 256 + threadIdx.x;        // 4,194,304 threads (16384 blocks)
    int t = idx & 4095, wh = idx >> 12;
    int w = wh >> 4, h = wh & 15;
    int ji = t >> 8, rem = t & 255;
    int j = ji >> 2, i = ji & 3;
    int q16 = rem >> 2, r = t & 3;
    int lq = q16 >> 4, lm = q16 & 15;
    int p = (i * 16 + lm) * 64 + j * 16 + lq * 4 + r;
    comb[idx] = bias[h * 4096 + p] + mask[w * 4096 + p];
}

// ---------------- K2: qkv GEMM, fp32-A async staging, counted-vmcnt(6) ----------------
// Tile 128x128, BK=32, 4 waves. Grid 12288 (1024 m-tiles x 12 nb); nb fastest after swizzle.
// Outputs (UNNORMALIZED): q_ws/k_ws [bw*16+h][n][dh] bf16, v_ws [bw*16+h][dh][n] bf16.
__global__ __launch_bounds__(256) void qkv_gemm_kernel(
    const float* __restrict__ x,    // [131072][512] fp32 (convert fused at frag read)
    const bf16* __restrict__ Wt,    // [1536][512]
    bf16* __restrict__ q_ws, bf16* __restrict__ k_ws, bf16* __restrict__ v_ws)
{
    __shared__ alignas(16) char Alds[2][16384];     // 128 rows x 32 fp32 (128 B), swizzled
    __shared__ alignas(16) char Blds[2][8192];      // 128 rows x 32 bf16 (64 B), linear
    const int bid = blockIdx.x, nwg = gridDim.x;
    const int wid = (bid & 7) * (nwg >> 3) + (bid >> 3);   // XCD-bijective (nwg%8==0)
    const int nb = wid % 12, mb = wid / 12;                // mb in [0, 1024)

    const int t = threadIdx.x;
    const int wv = t >> 6, lane = t & 63, lq = lane >> 4, lm = lane & 15;
    const int wr = wv >> 1, wc = wv & 1;

    const char* aBase = (const char*)x + (size_t)mb * 128 * 2048;   // fp32 row = 2048 B
    const char* bBase = (const char*)Wt + (size_t)(nb * 128) * 1024;

    // A: 4 chunks/thread, linear dest o = p*4096 + t*16, source pre-swizzled (involution)
    int arow[4], acol[4];
    #pragma unroll
    for (int p = 0; p < 4; ++p) {
        int s = swz32(p * 4096 + t * 16);
        arow[p] = s >> 7; acol[p] = s & 127;
    }
    // B: 2 chunks/thread, linear both sides (v9 layout)
    const int bo0 = t * 16, bo1 = 4096 + t * 16;
    const int brow0 = bo0 >> 6, bcol0 = bo0 & 63;
    const int brow1 = bo1 >> 6, bcol1 = bo1 & 63;

    auto stage = [&](int buf, int kt) {   // 6 gload_lds per thread (4 A fp32 + 2 B bf16)
        #pragma unroll
        for (int p = 0; p < 4; ++p)
            __builtin_amdgcn_global_load_lds(
                (const __attribute__((address_space(1))) void*)(aBase + (size_t)arow[p] * 2048 + kt * 128 + acol[p]),
                (__attribute__((address_space(3))) void*)(&Alds[buf][0] + p * 4096 + t * 16),
                16, 0, 0);
        __builtin_amdgcn_global_load_lds(
            (const __attribute__((address_space(1))) void*)(bBase + (size_t)brow0 * 1024 + kt * 64 + bcol0),
            (__attribute__((address_space(3))) void*)(&Blds[buf][0] + bo0), 16, 0, 0);
        __builtin_amdgcn_global_load_lds(
            (const __attribute__((address_space(1))) void*)(bBase + (size_t)brow1 * 1024 + kt * 64 + bcol1),
            (__attribute__((address_space(3))) void*)(&Blds[buf][0] + bo1), 16, 0, 0);
    };

    // read offsets: A swizzled (fp32, 2x16B per frag), B linear
    int aoff[4], boff[4];
    #pragma unroll
    for (int i = 0; i < 4; ++i) {
        int o0 = (wr * 64 + i * 16 + lm) * 128 + lq * 32;
        aoff[i] = swz32(o0);                          // +16 variant shares the row XOR
        boff[i] = (wc * 64 + i * 16 + lm) * 64 + lq * 16;
    }

    v4f acc[4][4];
    #pragma unroll
    for (int i = 0; i < 4; ++i)
        #pragma unroll
        for (int j = 0; j < 4; ++j) acc[i][j] = v4f{0.f, 0.f, 0.f, 0.f};

    stage(0, 0);
    #pragma unroll 1
    for (int kt = 0; kt < 16; ++kt) {
        if (kt < 15) {
            stage((kt + 1) & 1, kt + 1);              // next tile stays in flight across barriers
            asm volatile("s_waitcnt vmcnt(6)" ::: "memory");   // tile kt landed; kt+1 outstanding
        } else {
            asm volatile("s_waitcnt vmcnt(0)" ::: "memory");
        }
        __builtin_amdgcn_s_barrier();                 // publish tile kt
        __builtin_amdgcn_sched_barrier(0);
        const char* Ab = &Alds[kt & 1][0];
        const bf16* Bb = (const bf16*)&Blds[kt & 1][0];
        v8bf af[4], bfj[4];
        #pragma unroll
        for (int i = 0; i < 4; ++i) {
            v4f lo = *(const v4f*)(Ab + aoff[i]);
            v4f hi = *(const v4f*)(Ab + (aoff[i] ^ 16));
            af[i] = v8bf{ (bf16)lo[0], (bf16)lo[1], (bf16)lo[2], (bf16)lo[3],
                          (bf16)hi[0], (bf16)hi[1], (bf16)hi[2], (bf16)hi[3] };
        }
        #pragma unroll
        for (int j = 0; j < 4; ++j)
            bfj[j] = *(const v8bf*)(Bb + boff[j] / 2);   // boff in bytes -> bf16 elems
        #pragma unroll
        for (int i = 0; i < 4; ++i)
            #pragma unroll
            for (int j = 0; j < 4; ++j)
                acc[i][j] = __builtin_amdgcn_mfma_f32_16x16x32_bf16(af[i], bfj[j], acc[i][j], 0, 0, 0);
        __builtin_amdgcn_s_barrier();                 // reads done; buf may be overwritten next iter
    }

    // epilogue (v9-verified): row n = i*16+lq*4+r (window bw=mb*2+wr), col = nb*128+wc*64+j*16+lm
    const int bw = mb * 2 + wr;
    if (nb < 8) {
        bf16* dst = (nb < 4) ? q_ws : k_ws;
        const int hbase = (nb & 3) * 4 + wc * 2;
        #pragma unroll
        for (int tpair = 0; tpair < 2; ++tpair) {
            const int h = hbase + tpair;
            #pragma unroll
            for (int i = 0; i < 4; ++i)
                #pragma unroll
                for (int r = 0; r < 4; ++r) {
                    int n = i * 16 + lq * 4 + r;
                    size_t base = ((size_t)(bw * 16 + h) * 64 + n) * 32;
                    dst[base + lm]      = (bf16)acc[i][2 * tpair][r];
                    dst[base + 16 + lm] = (bf16)acc[i][2 * tpair + 1][r];
                }
        }
    } else {
        #pragma unroll
        for (int j = 0; j < 4; ++j) {
            const int h = (nb - 8) * 4 + wc * 2 + (j >> 1);
            const int dh = (j & 1) * 16 + lm;
            #pragma unroll
            for (int i = 0; i < 4; ++i) {
                v4bf pv = { (bf16)acc[i][j][0], (bf16)acc[i][j][1],
                            (bf16)acc[i][j][2], (bf16)acc[i][j][3] };
                *(v4bf*)(v_ws + ((size_t)(bw * 16 + h) * 32 + dh) * 64 + i * 16 + lq * 4) = pv;
            }
        }
    }
}

// ---------------- K3: attention, swapped QK^T, frag-local norm, 1 head/wave ----------------
__global__ __launch_bounds__(256) void attn_kernel(
    const bf16* __restrict__ q_ws,   // [bw*16+h][64][32] unnormalized
    const bf16* __restrict__ k_ws,
    const bf16* __restrict__ v_ws,   // [bw*16+h][32][64]
    const float* __restrict__ comb,  // [64][16][4096] swizzled for S^T frags
    const float* __restrict__ tau,   // [16]
    int wofs,
    bf16* __restrict__ attn_out)     // [rows][512]
{
    __shared__ alignas(16) bf16 P_all[4][64 * 72];
    const int blk = blockIdx.x;
    const int b = blk >> 2, g = blk & 3;
    const int tid = threadIdx.x;
    const int wv = tid >> 6, lane = tid & 63, lq = lane >> 4, lm = lane & 15;
    const int h = g * 4 + wv;
    const v4f z4 = {0.f, 0.f, 0.f, 0.f};

    bf16* P = P_all[wv];
    const size_t qk_base = (size_t)(b * 16 + h) * 64 * 32;
    const float* comb_hw = comb + ((size_t)(((wofs + b) & 63) * 16 + h)) * 4096
                                + (lq * 16 + lm) * 4;
    const float tau_h = tau[h];

    v8bf qf[4], kf[4];
    #pragma unroll
    for (int i = 0; i < 4; ++i)
        qf[i] = *(const v8bf*)(q_ws + qk_base + (i * 16 + lm) * 32 + lq * 8);
    #pragma unroll
    for (int j = 0; j < 4; ++j)
        kf[j] = *(const v8bf*)(k_ws + qk_base + (j * 16 + lm) * 32 + lq * 8);

    #pragma unroll
    for (int i = 0; i < 4; ++i) {
        float a = 0.f;
        #pragma unroll
        for (int e = 0; e < 8; ++e) { float f = (float)qf[i][e]; a = fmaf(f, f, a); }
        a += __shfl_xor(a, 16); a += __shfl_xor(a, 32);
        float sc = tau_h / fmaxf(sqrtf(a), 1e-12f);
        #pragma unroll
        for (int e = 0; e < 8; ++e) qf[i][e] = (bf16)((float)qf[i][e] * sc);
    }
    #pragma unroll
    for (int j = 0; j < 4; ++j) {
        float a = 0.f;
        #pragma unroll
        for (int e = 0; e < 8; ++e) { float f = (float)kf[j][e]; a = fmaf(f, f, a); }
        a += __shfl_xor(a, 16); a += __shfl_xor(a, 32);
        float sc = 1.0f / fmaxf(sqrtf(a), 1e-12f);
        #pragma unroll
        for (int e = 0; e < 8; ++e) kf[j][e] = (bf16)((float)kf[j][e] * sc);
    }

    v4f st[4][4];
    #pragma unroll
    for (int j = 0; j < 4; ++j)
        #pragma unroll
        for (int i = 0; i < 4; ++i)
            st[j][i] = __builtin_amdgcn_mfma_f32_16x16x32_bf16(kf[j], qf[i], z4, 0, 0, 0);

    #pragma unroll
    for (int j = 0; j < 4; ++j)
        #pragma unroll
        for (int i = 0; i < 4; ++i) {
            float4 cv = *(const float4*)(comb_hw + (j * 4 + i) * 256);
            st[j][i][0] += cv.x; st[j][i][1] += cv.y;
            st[j][i][2] += cv.z; st[j][i][3] += cv.w;
        }

    #pragma unroll
    for (int i = 0; i < 4; ++i) {
        float mx = st[0][i][0];
        #pragma unroll
        for (int j = 0; j < 4; ++j)
            #pragma unroll
            for (int r = 0; r < 4; ++r) mx = fmaxf(mx, st[j][i][r]);
        mx = fmaxf(mx, __shfl_xor(mx, 16));
        mx = fmaxf(mx, __shfl_xor(mx, 32));
        float sm = 0.f;
        #pragma unroll
        for (int j = 0; j < 4; ++j)
            #pragma unroll
            for (int r = 0; r < 4; ++r) {
                float e = __expf(st[j][i][r] - mx);
                st[j][i][r] = e; sm += e;
            }
        sm += __shfl_xor(sm, 16); sm += __shfl_xor(sm, 32);
        float rcp = 1.0f / sm;
        #pragma unroll
        for (int j = 0; j < 4; ++j) {
            v4bf pv = { (bf16)(st[j][i][0] * rcp), (bf16)(st[j][i][1] * rcp),
                        (bf16)(st[j][i][2] * rcp), (bf16)(st[j][i][3] * rcp) };
            *(v4bf*)(P + (i * 16 + lm) * 72 + j * 16 + lq * 4) = pv;
        }
    }

    const size_t v_base = (size_t)(b * 16 + h) * 32 * 64;
    v4f o[4][2];
    #pragma unroll
    for (int i = 0; i < 4; ++i)
        #pragma unroll
        for (int nt = 0; nt < 2; ++nt) o[i][nt] = z4;
    #pragma unroll
    for (int kk = 0; kk < 2; ++kk) {
        v8bf vf[2], pf[4];
        #pragma unroll
        for (int nt = 0; nt < 2; ++nt)
            vf[nt] = *(const v8bf*)(v_ws + v_base + (nt * 16 + lm) * 64 + kk * 32 + lq * 8);
        #pragma unroll
        for (int i = 0; i < 4; ++i)
            pf[i] = *(const v8bf*)(P + (i * 16 + lm) * 72 + kk * 32 + lq * 8);
        #pragma unroll
        for (int i = 0; i < 4; ++i)
            #pragma unroll
            for (int nt = 0; nt < 2; ++nt)
                o[i][nt] = __builtin_amdgcn_mfma_f32_16x16x32_bf16(pf[i], vf[nt], o[i][nt], 0, 0, 0);
    }
    #pragma unroll
    for (int i = 0; i < 4; ++i)
        #pragma unroll
        for (int nt = 0; nt < 2; ++nt)
            #pragma unroll
            for (int r = 0; r < 4; ++r)
                attn_out[(size_t)(b * 64 + i * 16 + lq * 4 + r) * 512 + h * 32 + nt * 16 + lm] =
                    (bf16)o[i][nt][r];
}

// ---------------- K4: out-projection GEMM, counted-vmcnt 2-buffer pipeline (v9) ----------------
__global__ __launch_bounds__(256) void proj_gemm_kernel(
    const bf16* __restrict__ A,     // [131072][512] attn_out
    const bf16* __restrict__ Bt,    // [512][512] WoT
    const float* __restrict__ b_out,
    float* __restrict__ out)        // [131072][512]
{
    __shared__ alignas(16) bf16 Alds[2][128 * 32];
    __shared__ alignas(16) bf16 Blds[2][128 * 32];
    const int bid = blockIdx.x;                       // 4096 blocks
    const int wid = (bid & 7) * 512 + (bid >> 3);     // XCD swizzle
    const int mb = wid >> 2, nb = wid & 3;            // nb fastest: A-tile reuse
    const int tid = threadIdx.x;
    const int wv = tid >> 6, lane = tid & 63, lq = lane >> 4, lm = lane & 15;
    const int wr = wv >> 1, wc = wv & 1;

    const char* aBase = (const char*)A + (size_t)mb * 128 * 1024;
    const char* bBase = (const char*)Bt + (size_t)nb * 128 * 1024;

    auto stage = [&](int buf, int kt) {
        #pragma unroll
        for (int p = 0; p < 2; ++p) {
            int idx = (p * 4 + wv) * 1024 + lane * 16;
            int row = idx >> 6, kb = idx & 63;
            __builtin_amdgcn_global_load_lds(
                (const __attribute__((address_space(1))) void*)(aBase + (size_t)row * 1024 + kt * 64 + kb),
                (__attribute__((address_space(3))) void*)((char*)Alds + buf * 8192 + (p * 4 + wv) * 1024),
                16, 0, 0);
            __builtin_amdgcn_global_load_lds(
                (const __attribute__((address_space(1))) void*)(bBase + (size_t)row * 1024 + kt * 64 + kb),
                (__attribute__((address_space(3))) void*)((char*)Blds + buf * 8192 + (p * 4 + wv) * 1024),
                16, 0, 0);
        }
    };

    v4f acc[4][4];
    #pragma unroll
    for (int i = 0; i < 4; ++i)
        #pragma unroll
        for (int j = 0; j < 4; ++j) acc[i][j] = v4f{0.f, 0.f, 0.f, 0.f};

    stage(0, 0);
    #pragma unroll 1
    for (int kt = 0; kt < 16; ++kt) {
        if (kt < 15) {
            stage((kt + 1) & 1, kt + 1);
            asm volatile("s_waitcnt vmcnt(4)" ::: "memory");
        } else {
            asm volatile("s_waitcnt vmcnt(0)" ::: "memory");
        }
        __builtin_amdgcn_s_barrier();
        __builtin_amdgcn_sched_barrier(0);
        const bf16* Ab = &Alds[kt & 1][0];
        const bf16* Bb = &Blds[kt & 1][0];
        v8bf af[4], bfj[4];
        #pragma unroll
        for (int i = 0; i < 4; ++i)
            af[i] = *(const v8bf*)(Ab + (wr * 64 + i * 16 + lm) * 32 + lq * 8);
        #pragma unroll
        for (int j = 0; j < 4; ++j)
            bfj[j] = *(const v8bf*)(Bb + (wc * 64 + j * 16 + lm) * 32 + lq * 8);
        #pragma unroll
        for (int i = 0; i < 4; ++i)
            #pragma unroll
            for (int j = 0; j < 4; ++j)
                acc[i][j] = __builtin_amdgcn_mfma_f32_16x16x32_bf16(af[i], bfj[j], acc[i][j], 0, 0, 0);
        __builtin_amdgcn_s_barrier();
    }

    #pragma unroll
    for (int j = 0; j < 4; ++j) {
        int col = nb * 128 + wc * 64 + j * 16 + lm;
        float bo = b_out[col];
        #pragma unroll
        for (int i = 0; i < 4; ++i)
            #pragma unroll
            for (int r = 0; r < 4; ++r)
                out[(size_t)(mb * 128 + wr * 64 + i * 16 + lq * 4 + r) * 512 + col] = acc[i][j][r] + bo;
    }
}

// ---------------- launch ----------------
extern "C" void kernel_launch(void* const* d_in, const int* in_sizes, int n_in,
                              void* d_out, int out_size, void* d_ws, size_t ws_size,
                              hipStream_t stream) {
    (void)in_sizes; (void)n_in; (void)out_size;
    const float* x       = (const float*)d_in[0];
    const float* mask    = (const float*)d_in[1];
    const float* w_qkv   = (const float*)d_in[2];
    const float* tau     = (const float*)d_in[3];
    const float* mlp_w1  = (const float*)d_in[4];
    const float* mlp_b1  = (const float*)d_in[5];
    const float* mlp_w2  = (const float*)d_in[6];
    const float* mlp_b2  = (const float*)d_in[7];
    const float* w_out   = (const float*)d_in[8];
    const float* b_out   = (const float*)d_in[9];
    const float* rel_log = (const float*)d_in[10];
    float* out = (float*)d_out;

    char* ws = (char*)d_ws;
    bf16*  Wt       = (bf16*)(ws);                   // 1,572,864 B
    bf16*  WoT      = (bf16*)(ws + 1572864);         //   524,288 B
    float* bias     = (float*)(ws + 2097152);        //   262,144 B
    float* comb     = (float*)(ws + 2359296);        //  16,777,216 B
    bf16*  attn_out = (bf16*)(ws + 19136512);        // 134,217,728 B
    char*  qkv_base = ws + 153354240;

    size_t avail = (ws_size > 153354240ULL) ? ws_size - 153354240ULL : 0;
    int W = 2048;                                    // 556 MB total; ws = 1 GiB (round-5 poison)
    while (W > 128 && (size_t)W * 196608ULL > avail) W >>= 1;
    const size_t qkbuf = (size_t)W * 65536;
    bf16* qb = (bf16*)qkv_base;
    bf16* kb = (bf16*)(qkv_base + qkbuf);
    bf16* vb = (bf16*)(qkv_base + 2 * qkbuf);

    convert_w_kernel<<<3072, 256, 0, stream>>>(w_qkv, w_out, Wt, WoT);
    bias_kernel<<<16, 256, 0, stream>>>(rel_log, mlp_w1, mlp_b1, mlp_w2, mlp_b2, bias);
    comb_kernel<<<16384, 256, 0, stream>>>(bias, mask, comb);

    const int nchunk = 2048 / W;
    for (int c = 0; c < nchunk; ++c) {
        const float* xc = x + (size_t)c * W * 64 * 512;
        bf16* aoc = attn_out + (size_t)c * W * 64 * 512;
        qkv_gemm_kernel<<<6 * W, 256, 0, stream>>>(xc, Wt, qb, kb, vb);
        attn_kernel<<<4 * W, 256, 0, stream>>>(qb, kb, vb, comb, tau, c * W, aoc);
    }
    proj_gemm_kernel<<<4096, 256, 0, stream>>>(attn_out, WoT, b_out, out);
}

// Round 15
// 745.388 us; speedup vs baseline: 1.1349x; 1.0111x over previous
//
#include <hip/hip_runtime.h>
#include <hip/hip_bf16.h>

// WindowAttentionV2: B_NW=2048, N=64, DIM=512, NH=16, DH=32, HID=384, NW=64
// v13 = v9 (qkv bf16 + counted-vmcnt, convert_x separate) + FUSED attn+proj:
//      one block per window (512 thr, 8 waves x 2 heads), O -> LDS tile, then
//      out-projection from LDS + L2-resident WoT, fp32 out + bias direct.
//      Removes attn_out 134MB write + 134MB read + one launch.

typedef __bf16 bf16;
typedef __bf16 v4bf __attribute__((ext_vector_type(4)));
typedef __bf16 v8bf __attribute__((ext_vector_type(8)));
typedef float  v4f  __attribute__((ext_vector_type(4)));

// ---------------- K0a: x fp32 -> bf16 (grid-stride) ----------------
__global__ void convert_x_kernel(const float* __restrict__ x, bf16* __restrict__ xbf) {
    const int stride = gridDim.x * 256;
    for (size_t idx = blockIdx.x * 256 + threadIdx.x; idx < 8388608; idx += stride) {
        const float4* xv = (const float4*)x;
        float4 v0 = xv[idx * 2];
        float4 v1 = xv[idx * 2 + 1];
        v8bf o = { (bf16)v0.x, (bf16)v0.y, (bf16)v0.z, (bf16)v0.w,
                   (bf16)v1.x, (bf16)v1.y, (bf16)v1.z, (bf16)v1.w };
        *(v8bf*)(xbf + idx * 8) = o;
    }
}

// ---------------- K0b: weights -> transposed bf16 ----------------
__global__ void convert_w_kernel(const float* __restrict__ wqkv, const float* __restrict__ wout,
                                 bf16* __restrict__ Wt, bf16* __restrict__ WoT) {
    int idx = blockIdx.x * 256 + threadIdx.x;        // 786,432 threads
    Wt[idx] = (bf16)wqkv[(idx & 511) * 1536 + (idx >> 9)];
    if (idx < 262144) WoT[idx] = (bf16)wout[(idx & 511) * 512 + (idx >> 9)];
}

// ---------------- K1a: meta-MLP bias[h][i][j] ----------------
__global__ void bias_kernel(const float* __restrict__ rel_log, const float* __restrict__ w1,
                            const float* __restrict__ b1, const float* __restrict__ w2,
                            const float* __restrict__ b2, float* __restrict__ bias) {
    int p = blockIdx.x * 256 + threadIdx.x;          // (i,j) pair, 4096 total
    float ra = rel_log[p * 2 + 0];
    float rb = rel_log[p * 2 + 1];
    float acc[16];
    #pragma unroll
    for (int t = 0; t < 16; ++t) acc[t] = 0.f;
    for (int kk = 0; kk < 384; ++kk) {
        float hv = fmaxf(ra * w1[kk] + rb * w1[384 + kk] + b1[kk], 0.f);
        #pragma unroll
        for (int t = 0; t < 16; ++t) acc[t] += hv * w2[kk * 16 + t];
    }
    #pragma unroll
    for (int t = 0; t < 16; ++t) bias[t * 4096 + p] = acc[t] + b2[t];
}

// ---------------- K1b: comb swizzled for the SWAPPED (S^T) frag layout ----------------
__global__ void comb_kernel(const float* __restrict__ bias, const float* __restrict__ mask,
                            float* __restrict__ comb) {
    int idx = blockIdx.x * 256 + threadIdx.x;        // 4,194,304 threads (16384 blocks)
    int t = idx & 4095, wh = idx >> 12;
    int w = wh >> 4, h = wh & 15;
    int ji = t >> 8, rem = t & 255;
    int j = ji >> 2, i = ji & 3;
    int q16 = rem >> 2, r = t & 3;
    int lq = q16 >> 4, lm = q16 & 15;
    int p = (i * 16 + lm) * 64 + j * 16 + lq * 4 + r;
    comb[idx] = bias[h * 4096 + p] + mask[w * 4096 + p];
}

// ---------------- K2: qkv GEMM, counted-vmcnt 2-buffer pipeline (v9, unchanged) ----------------
__global__ __launch_bounds__(256) void qkv_gemm_kernel(
    const bf16* __restrict__ xbf,   // [Mc][512] chunk rows, bf16
    const bf16* __restrict__ Wt,    // [1536][512]
    bf16* __restrict__ q_ws, bf16* __restrict__ k_ws, bf16* __restrict__ v_ws)
{
    __shared__ alignas(16) bf16 Alds[2][128 * 32];
    __shared__ alignas(16) bf16 Blds[2][128 * 32];
    const int bid = blockIdx.x, nwg = gridDim.x;
    const int wid = (bid & 7) * (nwg >> 3) + (bid >> 3);   // XCD-bijective (nwg%8==0)
    const int nb = wid % 12, mb = wid / 12;                // mb in [0, W/2)

    const int t = threadIdx.x;
    const int wv = t >> 6, lane = t & 63, lq = lane >> 4, lm = lane & 15;
    const int wr = wv >> 1, wc = wv & 1;

    const char* aBase = (const char*)xbf + (size_t)mb * 128 * 1024;
    const char* bBase = (const char*)Wt + (size_t)nb * 128 * 1024;

    auto stage = [&](int buf, int kt) {   // 4 global_load_lds per thread (2 A + 2 B)
        #pragma unroll
        for (int p = 0; p < 2; ++p) {
            int idx = (p * 4 + wv) * 1024 + lane * 16;     // byte offset in 8KB tile
            int row = idx >> 6, kb = idx & 63;
            __builtin_amdgcn_global_load_lds(
                (const __attribute__((address_space(1))) void*)(aBase + (size_t)row * 1024 + kt * 64 + kb),
                (__attribute__((address_space(3))) void*)((char*)Alds + buf * 8192 + (p * 4 + wv) * 1024),
                16, 0, 0);
            __builtin_amdgcn_global_load_lds(
                (const __attribute__((address_space(1))) void*)(bBase + (size_t)row * 1024 + kt * 64 + kb),
                (__attribute__((address_space(3))) void*)((char*)Blds + buf * 8192 + (p * 4 + wv) * 1024),
                16, 0, 0);
        }
    };

    v4f acc[4][4];
    #pragma unroll
    for (int i = 0; i < 4; ++i)
        #pragma unroll
        for (int j = 0; j < 4; ++j) acc[i][j] = v4f{0.f, 0.f, 0.f, 0.f};

    stage(0, 0);
    #pragma unroll 1
    for (int kt = 0; kt < 16; ++kt) {
        if (kt < 15) {
            stage((kt + 1) & 1, kt + 1);
            asm volatile("s_waitcnt vmcnt(4)" ::: "memory");
        } else {
            asm volatile("s_waitcnt vmcnt(0)" ::: "memory");
        }
        __builtin_amdgcn_s_barrier();
        __builtin_amdgcn_sched_barrier(0);
        const bf16* Ab = &Alds[kt & 1][0];
        const bf16* Bb = &Blds[kt & 1][0];
        v8bf af[4], bfj[4];
        #pragma unroll
        for (int i = 0; i < 4; ++i)
            af[i] = *(const v8bf*)(Ab + (wr * 64 + i * 16 + lm) * 32 + lq * 8);
        #pragma unroll
        for (int j = 0; j < 4; ++j)
            bfj[j] = *(const v8bf*)(Bb + (wc * 64 + j * 16 + lm) * 32 + lq * 8);
        #pragma unroll
        for (int i = 0; i < 4; ++i)
            #pragma unroll
            for (int j = 0; j < 4; ++j)
                acc[i][j] = __builtin_amdgcn_mfma_f32_16x16x32_bf16(af[i], bfj[j], acc[i][j], 0, 0, 0);
        __builtin_amdgcn_s_barrier();
    }

    const int bw = mb * 2 + wr;
    if (nb < 8) {
        bf16* dst = (nb < 4) ? q_ws : k_ws;
        const int hbase = (nb & 3) * 4 + wc * 2;
        #pragma unroll
        for (int tpair = 0; tpair < 2; ++tpair) {
            const int h = hbase + tpair;
            #pragma unroll
            for (int i = 0; i < 4; ++i)
                #pragma unroll
                for (int r = 0; r < 4; ++r) {
                    int n = i * 16 + lq * 4 + r;
                    size_t base = ((size_t)(bw * 16 + h) * 64 + n) * 32;
                    dst[base + lm]      = (bf16)acc[i][2 * tpair][r];
                    dst[base + 16 + lm] = (bf16)acc[i][2 * tpair + 1][r];
                }
        }
    } else {
        #pragma unroll
        for (int j = 0; j < 4; ++j) {
            const int h = (nb - 8) * 4 + wc * 2 + (j >> 1);
            const int dh = (j & 1) * 16 + lm;
            #pragma unroll
            for (int i = 0; i < 4; ++i) {
                v4bf pv = { (bf16)acc[i][j][0], (bf16)acc[i][j][1],
                            (bf16)acc[i][j][2], (bf16)acc[i][j][3] };
                *(v4bf*)(v_ws + ((size_t)(bw * 16 + h) * 32 + dh) * 64 + i * 16 + lq * 4) = pv;
            }
        }
    }
}

// ---------------- K3: FUSED attention + out-projection, one window per block ----------------
// 512 thr = 8 waves; wave wv handles heads {2wv, 2wv+1}; O -> AO_lds; then proj:
// wave wv computes out cols [wv*64, wv*64+64), K-loop over 512 from AO_lds, B from WoT (L2).
__global__ __launch_bounds__(512) void attn_proj_kernel(
    const bf16* __restrict__ q_ws,   // [bw*16+h][64][32] unnormalized
    const bf16* __restrict__ k_ws,
    const bf16* __restrict__ v_ws,   // [bw*16+h][32][64]
    const float* __restrict__ comb,  // [64][16][4096] swizzled for S^T frags
    const float* __restrict__ tau,   // [16]
    const bf16* __restrict__ WoT,    // [512][512] (out-col major rows)
    const float* __restrict__ b_out, // [512]
    int wofs,
    float* __restrict__ out)         // chunk slice, [rows][512] fp32
{
    __shared__ alignas(16) bf16 AO[64 * 520];        // attn output tile, stride 520
    __shared__ alignas(16) bf16 P_all[8][64 * 72];
    const int b = blockIdx.x;
    const int tid = threadIdx.x;
    const int wv = tid >> 6, lane = tid & 63, lq = lane >> 4, lm = lane & 15;
    const v4f z4 = {0.f, 0.f, 0.f, 0.f};
    bf16* P = P_all[wv];

    #pragma unroll 1
    for (int hh = 0; hh < 2; ++hh) {
        const int h = wv * 2 + hh;
        const size_t qk_base = (size_t)(b * 16 + h) * 64 * 32;
        const float* comb_hw = comb + ((size_t)(((wofs + b) & 63) * 16 + h)) * 4096
                                    + (lq * 16 + lm) * 4;
        const float tau_h = tau[h];

        v8bf qf[4], kf[4];
        #pragma unroll
        for (int i = 0; i < 4; ++i)
            qf[i] = *(const v8bf*)(q_ws + qk_base + (i * 16 + lm) * 32 + lq * 8);
        #pragma unroll
        for (int j = 0; j < 4; ++j)
            kf[j] = *(const v8bf*)(k_ws + qk_base + (j * 16 + lm) * 32 + lq * 8);

        // frag-local L2 norms: 8 in-lane squares + 2 shfl; tau folded into q-scale
        #pragma unroll
        for (int i = 0; i < 4; ++i) {
            float a = 0.f;
            #pragma unroll
            for (int e = 0; e < 8; ++e) { float f = (float)qf[i][e]; a = fmaf(f, f, a); }
            a += __shfl_xor(a, 16); a += __shfl_xor(a, 32);
            float sc = tau_h / fmaxf(sqrtf(a), 1e-12f);
            #pragma unroll
            for (int e = 0; e < 8; ++e) qf[i][e] = (bf16)((float)qf[i][e] * sc);
        }
        #pragma unroll
        for (int j = 0; j < 4; ++j) {
            float a = 0.f;
            #pragma unroll
            for (int e = 0; e < 8; ++e) { float f = (float)kf[j][e]; a = fmaf(f, f, a); }
            a += __shfl_xor(a, 16); a += __shfl_xor(a, 32);
            float sc = 1.0f / fmaxf(sqrtf(a), 1e-12f);
            #pragma unroll
            for (int e = 0; e < 8; ++e) kf[j][e] = (bf16)((float)kf[j][e] * sc);
        }

        // S^T = K̂ Q̂^T: lane holds (k = j*16+lq*4+r, q = i*16+lm)
        v4f st[4][4];
        #pragma unroll
        for (int j = 0; j < 4; ++j)
            #pragma unroll
            for (int i = 0; i < 4; ++i)
                st[j][i] = __builtin_amdgcn_mfma_f32_16x16x32_bf16(kf[j], qf[i], z4, 0, 0, 0);

        #pragma unroll
        for (int j = 0; j < 4; ++j)
            #pragma unroll
            for (int i = 0; i < 4; ++i) {
                float4 cv = *(const float4*)(comb_hw + (j * 4 + i) * 256);
                st[j][i][0] += cv.x; st[j][i][1] += cv.y;
                st[j][i][2] += cv.z; st[j][i][3] += cv.w;
            }

        // softmax over k per q-col i: 16 in-lane + 2 shfl; fold 1/l into P
        #pragma unroll
        for (int i = 0; i < 4; ++i) {
            float mx = st[0][i][0];
            #pragma unroll
            for (int j = 0; j < 4; ++j)
                #pragma unroll
                for (int r = 0; r < 4; ++r) mx = fmaxf(mx, st[j][i][r]);
            mx = fmaxf(mx, __shfl_xor(mx, 16));
            mx = fmaxf(mx, __shfl_xor(mx, 32));
            float sm = 0.f;
            #pragma unroll
            for (int j = 0; j < 4; ++j)
                #pragma unroll
                for (int r = 0; r < 4; ++r) {
                    float e = __expf(st[j][i][r] - mx);
                    st[j][i][r] = e; sm += e;
                }
            sm += __shfl_xor(sm, 16); sm += __shfl_xor(sm, 32);
            float rcp = 1.0f / sm;
            #pragma unroll
            for (int j = 0; j < 4; ++j) {
                v4bf pv = { (bf16)(st[j][i][0] * rcp), (bf16)(st[j][i][1] * rcp),
                            (bf16)(st[j][i][2] * rcp), (bf16)(st[j][i][3] * rcp) };
                *(v4bf*)(P + (i * 16 + lm) * 72 + j * 16 + lq * 4) = pv;
            }
        }

        // O = P̂ V; write to AO_lds (cols h*32 .. h*32+31)
        const size_t v_base = (size_t)(b * 16 + h) * 32 * 64;
        v4f o[4][2];
        #pragma unroll
        for (int i = 0; i < 4; ++i)
            #pragma unroll
            for (int nt = 0; nt < 2; ++nt) o[i][nt] = z4;
        #pragma unroll
        for (int kk = 0; kk < 2; ++kk) {
            v8bf vf[2], pf[4];
            #pragma unroll
            for (int nt = 0; nt < 2; ++nt)
                vf[nt] = *(const v8bf*)(v_ws + v_base + (nt * 16 + lm) * 64 + kk * 32 + lq * 8);
            #pragma unroll
            for (int i = 0; i < 4; ++i)
                pf[i] = *(const v8bf*)(P + (i * 16 + lm) * 72 + kk * 32 + lq * 8);
            #pragma unroll
            for (int i = 0; i < 4; ++i)
                #pragma unroll
                for (int nt = 0; nt < 2; ++nt)
                    o[i][nt] = __builtin_amdgcn_mfma_f32_16x16x32_bf16(pf[i], vf[nt], o[i][nt], 0, 0, 0);
        }
        #pragma unroll
        for (int i = 0; i < 4; ++i)
            #pragma unroll
            for (int nt = 0; nt < 2; ++nt)
                #pragma unroll
                for (int r = 0; r < 4; ++r)
                    AO[(i * 16 + lq * 4 + r) * 520 + h * 32 + nt * 16 + lm] = (bf16)o[i][nt][r];
    }

    __syncthreads();

    // ---- out-projection: rows 0..63 x cols wv*64..wv*64+63, K=512 ----
    v4f acc[4][4];
    #pragma unroll
    for (int i = 0; i < 4; ++i)
        #pragma unroll
        for (int j = 0; j < 4; ++j) acc[i][j] = v4f{0.f, 0.f, 0.f, 0.f};

    #pragma unroll 2
    for (int kc = 0; kc < 16; ++kc) {
        v8bf af[4], bfj[4];
        #pragma unroll
        for (int j = 0; j < 4; ++j)
            bfj[j] = *(const v8bf*)(WoT + (size_t)(wv * 64 + j * 16 + lm) * 512 + kc * 32 + lq * 8);
        #pragma unroll
        for (int i = 0; i < 4; ++i)
            af[i] = *(const v8bf*)(AO + (i * 16 + lm) * 520 + kc * 32 + lq * 8);
        #pragma unroll
        for (int i = 0; i < 4; ++i)
            #pragma unroll
            for (int j = 0; j < 4; ++j)
                acc[i][j] = __builtin_amdgcn_mfma_f32_16x16x32_bf16(af[i], bfj[j], acc[i][j], 0, 0, 0);
    }

    #pragma unroll
    for (int j = 0; j < 4; ++j) {
        const int col = wv * 64 + j * 16 + lm;
        const float bo = b_out[col];
        #pragma unroll
        for (int i = 0; i < 4; ++i)
            #pragma unroll
            for (int r = 0; r < 4; ++r)
                out[(size_t)(b * 64 + i * 16 + lq * 4 + r) * 512 + col] = acc[i][j][r] + bo;
    }
}

// ---------------- launch ----------------
extern "C" void kernel_launch(void* const* d_in, const int* in_sizes, int n_in,
                              void* d_out, int out_size, void* d_ws, size_t ws_size,
                              hipStream_t stream) {
    (void)in_sizes; (void)n_in; (void)out_size;
    const float* x       = (const float*)d_in[0];
    const float* mask    = (const float*)d_in[1];
    const float* w_qkv   = (const float*)d_in[2];
    const float* tau     = (const float*)d_in[3];
    const float* mlp_w1  = (const float*)d_in[4];
    const float* mlp_b1  = (const float*)d_in[5];
    const float* mlp_w2  = (const float*)d_in[6];
    const float* mlp_b2  = (const float*)d_in[7];
    const float* w_out   = (const float*)d_in[8];
    const float* b_out   = (const float*)d_in[9];
    const float* rel_log = (const float*)d_in[10];
    float* out = (float*)d_out;

    char* ws = (char*)d_ws;
    bf16*  Wt     = (bf16*)(ws);                     // 1,572,864 B
    bf16*  WoT    = (bf16*)(ws + 1572864);           //   524,288 B
    float* bias   = (float*)(ws + 2097152);          //   262,144 B
    float* comb   = (float*)(ws + 2359296);          //  16,777,216 B
    bf16*  xbf    = (bf16*)(ws + 19136512);          // 134,217,728 B
    char*  qkv_base = ws + 153354240;

    size_t avail = (ws_size > 153354240ULL) ? ws_size - 153354240ULL : 0;
    int W = 2048;                                    // 556 MB total; ws = 1 GiB (round-5 poison)
    while (W > 128 && (size_t)W * 196608ULL > avail) W >>= 1;
    const size_t qkbuf = (size_t)W * 65536;
    bf16* qb = (bf16*)qkv_base;
    bf16* kb = (bf16*)(qkv_base + qkbuf);
    bf16* vb = (bf16*)(qkv_base + 2 * qkbuf);

    convert_w_kernel<<<3072, 256, 0, stream>>>(w_qkv, w_out, Wt, WoT);
    bias_kernel<<<16, 256, 0, stream>>>(rel_log, mlp_w1, mlp_b1, mlp_w2, mlp_b2, bias);
    comb_kernel<<<16384, 256, 0, stream>>>(bias, mask, comb);
    convert_x_kernel<<<2048, 256, 0, stream>>>(x, xbf);

    const int nchunk = 2048 / W;
    for (int c = 0; c < nchunk; ++c) {
        bf16* slice = xbf + (size_t)c * W * 64 * 512;
        qkv_gemm_kernel<<<6 * W, 256, 0, stream>>>(slice, Wt, qb, kb, vb);
        attn_proj_kernel<<<W, 512, 0, stream>>>(qb, kb, vb, comb, tau, WoT, b_out,
                                                c * W, out + (size_t)c * W * 64 * 512);
    }
}

// Round 16
// 736.674 us; speedup vs baseline: 1.1483x; 1.0118x over previous
//
#include <hip/hip_runtime.h>
#include <hip/hip_bf16.h>

// WindowAttentionV2: B_NW=2048, N=64, DIM=512, NH=16, DH=32, HID=384, NW=64
// v14: qkv reads x fp32 DIRECTLY, once: block owns 128-row m-tile, A converted to
//      bf16 into 128KB swizzled LDS, reused across 6 passes x 256 cols (B dbuf
//      global_load_lds, counted vmcnt(2)). Deletes convert_x + xbf buffer.
//      attn+proj fused kernel = v13. LDS = exactly 160 KiB.

typedef __bf16 bf16;
typedef __bf16 v4bf __attribute__((ext_vector_type(4)));
typedef __bf16 v8bf __attribute__((ext_vector_type(8)));
typedef float  v4f  __attribute__((ext_vector_type(4)));

#define AS1 __attribute__((address_space(1)))
#define AS3 __attribute__((address_space(3)))

// A-tile involution: rows stride 1024B; XOR row low-3 bits (o bits 10-12) into 16B-slot bits 4-6.
__device__ __forceinline__ int swzA(int o) { return o ^ (((o >> 10) & 7) << 4); }

// ---------------- K0: weights -> transposed bf16 ----------------
__global__ void convert_w_kernel(const float* __restrict__ wqkv, const float* __restrict__ wout,
                                 bf16* __restrict__ Wt, bf16* __restrict__ WoT) {
    int idx = blockIdx.x * 256 + threadIdx.x;        // 786,432 threads
    Wt[idx] = (bf16)wqkv[(idx & 511) * 1536 + (idx >> 9)];
    if (idx < 262144) WoT[idx] = (bf16)wout[(idx & 511) * 512 + (idx >> 9)];
}

// ---------------- K1a: meta-MLP bias[h][i][j] ----------------
__global__ void bias_kernel(const float* __restrict__ rel_log, const float* __restrict__ w1,
                            const float* __restrict__ b1, const float* __restrict__ w2,
                            const float* __restrict__ b2, float* __restrict__ bias) {
    int p = blockIdx.x * 256 + threadIdx.x;          // (i,j) pair, 4096 total
    float ra = rel_log[p * 2 + 0];
    float rb = rel_log[p * 2 + 1];
    float acc[16];
    #pragma unroll
    for (int t = 0; t < 16; ++t) acc[t] = 0.f;
    for (int kk = 0; kk < 384; ++kk) {
        float hv = fmaxf(ra * w1[kk] + rb * w1[384 + kk] + b1[kk], 0.f);
        #pragma unroll
        for (int t = 0; t < 16; ++t) acc[t] += hv * w2[kk * 16 + t];
    }
    #pragma unroll
    for (int t = 0; t < 16; ++t) bias[t * 4096 + p] = acc[t] + b2[t];
}

// ---------------- K1b: comb swizzled for the SWAPPED (S^T) frag layout ----------------
__global__ void comb_kernel(const float* __restrict__ bias, const float* __restrict__ mask,
                            float* __restrict__ comb) {
    int idx = blockIdx.x * 256 + threadIdx.x;        // 4,194,304 threads (16384 blocks)
    int t = idx & 4095, wh = idx >> 12;
    int w = wh >> 4, h = wh & 15;
    int ji = t >> 8, rem = t & 255;
    int j = ji >> 2, i = ji & 3;
    int q16 = rem >> 2, r = t & 3;
    int lq = q16 >> 4, lm = q16 & 15;
    int p = (i * 16 + lm) * 64 + j * 16 + lq * 4 + r;
    comb[idx] = bias[h * 4096 + p] + mask[w * 4096 + p];
}

// ---------------- K2: qkv fused GEMM: A staged ONCE (fp32->bf16), 6 col-passes ----------------
// Grid = W/2 blocks (one per 128-row m-tile), 512 thr = 8 waves (2x4 of 64x64 wave tiles).
// Outputs (UNNORMALIZED): q_ws/k_ws [bw*16+h][n][dh] bf16, v_ws [bw*16+h][dh][n] bf16.
__global__ __launch_bounds__(512) void qkv_fused_kernel(
    const float* __restrict__ x,    // [Mc][512] fp32 chunk rows
    const bf16* __restrict__ Wt,    // [1536][512]
    bf16* __restrict__ q_ws, bf16* __restrict__ k_ws, bf16* __restrict__ v_ws)
{
    __shared__ alignas(16) char Albuf[131072];       // A: 128 x 512 bf16, swizzled
    __shared__ alignas(16) char Blbuf[2][16384];     // B: 256 rows x 32 K bf16, linear, dbuf
    const int mb = blockIdx.x;
    const int t = threadIdx.x;
    const int wv = t >> 6, lane = t & 63, lq = lane >> 4, lm = lane & 15;
    const int wr = wv >> 2, wc = wv & 3;             // wave tile: rows wr*64, cols wc*64

    auto stageB = [&](int buf, int pass, int kt) {   // 2 gload_lds per thread (16 KB tile)
        const char* bBase = (const char*)Wt + (size_t)(pass * 256) * 1024;
        #pragma unroll
        for (int p = 0; p < 2; ++p) {
            int o = p * 8192 + t * 16;
            __builtin_amdgcn_global_load_lds(
                (const AS1 void*)(bBase + (size_t)(o >> 6) * 1024 + kt * 64 + (o & 63)),
                (AS3 void*)(&Blbuf[buf][0] + o), 16, 0, 0);
        }
    };

    stageB(0, 0, 0);                                  // B(0,0) in flight during A-stage

    // ---- A-stage: x fp32 -> bf16 LDS, read ONCE, swizzled write ----
    {
        const char* xbase = (const char*)x + (size_t)mb * 128 * 2048;
        #pragma unroll
        for (int p = 0; p < 16; ++p) {
            int o = p * 8192 + t * 16;                // bf16-byte offset in A tile
            const float4* src = (const float4*)(xbase + (size_t)o * 2);
            float4 f0 = src[0], f1 = src[1];
            v8bf a = { (bf16)f0.x, (bf16)f0.y, (bf16)f0.z, (bf16)f0.w,
                       (bf16)f1.x, (bf16)f1.y, (bf16)f1.z, (bf16)f1.w };
            *(v8bf*)(&Albuf[swzA(o)]) = a;
        }
    }
    __syncthreads();                                  // drains A ds_writes + B(0,0)

    // frag read offsets: A swizzled base (kt folded by XOR: bit-fields disjoint), B linear
    int abase[4], boff[4];
    #pragma unroll
    for (int i = 0; i < 4; ++i) {
        int row = wr * 64 + i * 16 + lm;
        abase[i] = (row * 1024 + lq * 16) ^ ((row & 7) << 4);
        boff[i] = (wc * 64 + i * 16 + lm) * 64 + lq * 16;
    }

    v4f acc[4][4];
    #pragma unroll
    for (int i = 0; i < 4; ++i)
        #pragma unroll
        for (int j = 0; j < 4; ++j) acc[i][j] = v4f{0.f, 0.f, 0.f, 0.f};

    const int bw = mb * 2 + wr;

    #pragma unroll 1
    for (int ph = 0; ph < 96; ++ph) {
        const int pass = ph >> 4, kt = ph & 15;
        if (ph < 95) {
            const int nph = ph + 1;
            stageB(nph & 1, nph >> 4, nph & 15);      // next B stays in flight across barriers
            asm volatile("s_waitcnt vmcnt(2)" ::: "memory");
        } else {
            asm volatile("s_waitcnt vmcnt(0)" ::: "memory");
        }
        __builtin_amdgcn_s_barrier();
        __builtin_amdgcn_sched_barrier(0);
        const char* Bb = &Blbuf[ph & 1][0];
        v8bf af[4], bfj[4];
        #pragma unroll
        for (int i = 0; i < 4; ++i) af[i] = *(const v8bf*)(&Albuf[abase[i] ^ (kt << 6)]);
        #pragma unroll
        for (int j = 0; j < 4; ++j) bfj[j] = *(const v8bf*)(Bb + boff[j]);
        #pragma unroll
        for (int i = 0; i < 4; ++i)
            #pragma unroll
            for (int j = 0; j < 4; ++j)
                acc[i][j] = __builtin_amdgcn_mfma_f32_16x16x32_bf16(af[i], bfj[j], acc[i][j], 0, 0, 0);
        __builtin_amdgcn_s_barrier();

        if (kt == 15) {
            // ---- epilogue for this pass: cols = pass*256 + wc*64 + j*16 + lm ----
            const int hbase = (pass & 1) * 8 + wc * 2;
            if (pass < 4) {
                bf16* dst = (pass < 2) ? q_ws : k_ws;
                #pragma unroll
                for (int tpair = 0; tpair < 2; ++tpair) {
                    const int h = hbase + tpair;
                    #pragma unroll
                    for (int i = 0; i < 4; ++i)
                        #pragma unroll
                        for (int r = 0; r < 4; ++r) {
                            int n = i * 16 + lq * 4 + r;
                            size_t base = ((size_t)(bw * 16 + h) * 64 + n) * 32;
                            dst[base + lm]      = (bf16)acc[i][2 * tpair][r];
                            dst[base + 16 + lm] = (bf16)acc[i][2 * tpair + 1][r];
                        }
                }
            } else {
                #pragma unroll
                for (int j = 0; j < 4; ++j) {
                    const int h = hbase + (j >> 1);
                    const int dh = (j & 1) * 16 + lm;
                    #pragma unroll
                    for (int i = 0; i < 4; ++i) {
                        v4bf pv = { (bf16)acc[i][j][0], (bf16)acc[i][j][1],
                                    (bf16)acc[i][j][2], (bf16)acc[i][j][3] };
                        *(v4bf*)(v_ws + ((size_t)(bw * 16 + h) * 32 + dh) * 64 + i * 16 + lq * 4) = pv;
                    }
                }
            }
            #pragma unroll
            for (int i = 0; i < 4; ++i)
                #pragma unroll
                for (int j = 0; j < 4; ++j) acc[i][j] = v4f{0.f, 0.f, 0.f, 0.f};
        }
    }
}

// ---------------- K3: FUSED attention + out-projection (v13, unchanged) ----------------
__global__ __launch_bounds__(512) void attn_proj_kernel(
    const bf16* __restrict__ q_ws,   // [bw*16+h][64][32] unnormalized
    const bf16* __restrict__ k_ws,
    const bf16* __restrict__ v_ws,   // [bw*16+h][32][64]
    const float* __restrict__ comb,  // [64][16][4096] swizzled for S^T frags
    const float* __restrict__ tau,   // [16]
    const bf16* __restrict__ WoT,    // [512][512]
    const float* __restrict__ b_out, // [512]
    int wofs,
    float* __restrict__ out)         // chunk slice, [rows][512] fp32
{
    __shared__ alignas(16) bf16 AO[64 * 520];
    __shared__ alignas(16) bf16 P_all[8][64 * 72];
    const int b = blockIdx.x;
    const int tid = threadIdx.x;
    const int wv = tid >> 6, lane = tid & 63, lq = lane >> 4, lm = lane & 15;
    const v4f z4 = {0.f, 0.f, 0.f, 0.f};
    bf16* P = P_all[wv];

    #pragma unroll 1
    for (int hh = 0; hh < 2; ++hh) {
        const int h = wv * 2 + hh;
        const size_t qk_base = (size_t)(b * 16 + h) * 64 * 32;
        const float* comb_hw = comb + ((size_t)(((wofs + b) & 63) * 16 + h)) * 4096
                                    + (lq * 16 + lm) * 4;
        const float tau_h = tau[h];

        v8bf qf[4], kf[4];
        #pragma unroll
        for (int i = 0; i < 4; ++i)
            qf[i] = *(const v8bf*)(q_ws + qk_base + (i * 16 + lm) * 32 + lq * 8);
        #pragma unroll
        for (int j = 0; j < 4; ++j)
            kf[j] = *(const v8bf*)(k_ws + qk_base + (j * 16 + lm) * 32 + lq * 8);

        #pragma unroll
        for (int i = 0; i < 4; ++i) {
            float a = 0.f;
            #pragma unroll
            for (int e = 0; e < 8; ++e) { float f = (float)qf[i][e]; a = fmaf(f, f, a); }
            a += __shfl_xor(a, 16); a += __shfl_xor(a, 32);
            float sc = tau_h / fmaxf(sqrtf(a), 1e-12f);
            #pragma unroll
            for (int e = 0; e < 8; ++e) qf[i][e] = (bf16)((float)qf[i][e] * sc);
        }
        #pragma unroll
        for (int j = 0; j < 4; ++j) {
            float a = 0.f;
            #pragma unroll
            for (int e = 0; e < 8; ++e) { float f = (float)kf[j][e]; a = fmaf(f, f, a); }
            a += __shfl_xor(a, 16); a += __shfl_xor(a, 32);
            float sc = 1.0f / fmaxf(sqrtf(a), 1e-12f);
            #pragma unroll
            for (int e = 0; e < 8; ++e) kf[j][e] = (bf16)((float)kf[j][e] * sc);
        }

        v4f st[4][4];
        #pragma unroll
        for (int j = 0; j < 4; ++j)
            #pragma unroll
            for (int i = 0; i < 4; ++i)
                st[j][i] = __builtin_amdgcn_mfma_f32_16x16x32_bf16(kf[j], qf[i], z4, 0, 0, 0);

        #pragma unroll
        for (int j = 0; j < 4; ++j)
            #pragma unroll
            for (int i = 0; i < 4; ++i) {
                float4 cv = *(const float4*)(comb_hw + (j * 4 + i) * 256);
                st[j][i][0] += cv.x; st[j][i][1] += cv.y;
                st[j][i][2] += cv.z; st[j][i][3] += cv.w;
            }

        #pragma unroll
        for (int i = 0; i < 4; ++i) {
            float mx = st[0][i][0];
            #pragma unroll
            for (int j = 0; j < 4; ++j)
                #pragma unroll
                for (int r = 0; r < 4; ++r) mx = fmaxf(mx, st[j][i][r]);
            mx = fmaxf(mx, __shfl_xor(mx, 16));
            mx = fmaxf(mx, __shfl_xor(mx, 32));
            float sm = 0.f;
            #pragma unroll
            for (int j = 0; j < 4; ++j)
                #pragma unroll
                for (int r = 0; r < 4; ++r) {
                    float e = __expf(st[j][i][r] - mx);
                    st[j][i][r] = e; sm += e;
                }
            sm += __shfl_xor(sm, 16); sm += __shfl_xor(sm, 32);
            float rcp = 1.0f / sm;
            #pragma unroll
            for (int j = 0; j < 4; ++j) {
                v4bf pv = { (bf16)(st[j][i][0] * rcp), (bf16)(st[j][i][1] * rcp),
                            (bf16)(st[j][i][2] * rcp), (bf16)(st[j][i][3] * rcp) };
                *(v4bf*)(P + (i * 16 + lm) * 72 + j * 16 + lq * 4) = pv;
            }
        }

        const size_t v_base = (size_t)(b * 16 + h) * 32 * 64;
        v4f o[4][2];
        #pragma unroll
        for (int i = 0; i < 4; ++i)
            #pragma unroll
            for (int nt = 0; nt < 2; ++nt) o[i][nt] = z4;
        #pragma unroll
        for (int kk = 0; kk < 2; ++kk) {
            v8bf vf[2], pf[4];
            #pragma unroll
            for (int nt = 0; nt < 2; ++nt)
                vf[nt] = *(const v8bf*)(v_ws + v_base + (nt * 16 + lm) * 64 + kk * 32 + lq * 8);
            #pragma unroll
            for (int i = 0; i < 4; ++i)
                pf[i] = *(const v8bf*)(P + (i * 16 + lm) * 72 + kk * 32 + lq * 8);
            #pragma unroll
            for (int i = 0; i < 4; ++i)
                #pragma unroll
                for (int nt = 0; nt < 2; ++nt)
                    o[i][nt] = __builtin_amdgcn_mfma_f32_16x16x32_bf16(pf[i], vf[nt], o[i][nt], 0, 0, 0);
        }
        #pragma unroll
        for (int i = 0; i < 4; ++i)
            #pragma unroll
            for (int nt = 0; nt < 2; ++nt)
                #pragma unroll
                for (int r = 0; r < 4; ++r)
                    AO[(i * 16 + lq * 4 + r) * 520 + h * 32 + nt * 16 + lm] = (bf16)o[i][nt][r];
    }

    __syncthreads();

    // ---- out-projection: rows 0..63 x cols wv*64..wv*64+63, K=512 ----
    v4f acc[4][4];
    #pragma unroll
    for (int i = 0; i < 4; ++i)
        #pragma unroll
        for (int j = 0; j < 4; ++j) acc[i][j] = v4f{0.f, 0.f, 0.f, 0.f};

    #pragma unroll 2
    for (int kc = 0; kc < 16; ++kc) {
        v8bf af[4], bfj[4];
        #pragma unroll
        for (int j = 0; j < 4; ++j)
            bfj[j] = *(const v8bf*)(WoT + (size_t)(wv * 64 + j * 16 + lm) * 512 + kc * 32 + lq * 8);
        #pragma unroll
        for (int i = 0; i < 4; ++i)
            af[i] = *(const v8bf*)(AO + (i * 16 + lm) * 520 + kc * 32 + lq * 8);
        #pragma unroll
        for (int i = 0; i < 4; ++i)
            #pragma unroll
            for (int j = 0; j < 4; ++j)
                acc[i][j] = __builtin_amdgcn_mfma_f32_16x16x32_bf16(af[i], bfj[j], acc[i][j], 0, 0, 0);
    }

    #pragma unroll
    for (int j = 0; j < 4; ++j) {
        const int col = wv * 64 + j * 16 + lm;
        const float bo = b_out[col];
        #pragma unroll
        for (int i = 0; i < 4; ++i)
            #pragma unroll
            for (int r = 0; r < 4; ++r)
                out[(size_t)(b * 64 + i * 16 + lq * 4 + r) * 512 + col] = acc[i][j][r] + bo;
    }
}

// ---------------- launch ----------------
extern "C" void kernel_launch(void* const* d_in, const int* in_sizes, int n_in,
                              void* d_out, int out_size, void* d_ws, size_t ws_size,
                              hipStream_t stream) {
    (void)in_sizes; (void)n_in; (void)out_size;
    const float* x       = (const float*)d_in[0];
    const float* mask    = (const float*)d_in[1];
    const float* w_qkv   = (const float*)d_in[2];
    const float* tau     = (const float*)d_in[3];
    const float* mlp_w1  = (const float*)d_in[4];
    const float* mlp_b1  = (const float*)d_in[5];
    const float* mlp_w2  = (const float*)d_in[6];
    const float* mlp_b2  = (const float*)d_in[7];
    const float* w_out   = (const float*)d_in[8];
    const float* b_out   = (const float*)d_in[9];
    const float* rel_log = (const float*)d_in[10];
    float* out = (float*)d_out;

    char* ws = (char*)d_ws;
    bf16*  Wt     = (bf16*)(ws);                     // 1,572,864 B
    bf16*  WoT    = (bf16*)(ws + 1572864);           //   524,288 B
    float* bias   = (float*)(ws + 2097152);          //   262,144 B
    float* comb   = (float*)(ws + 2359296);          //  16,777,216 B
    char*  qkv_base = ws + 19136512;                 // no xbf anymore

    // W windows per chunk; qkv buffers 3*W*65536 B. ws top = 19,136,512 + 3*W*65536.
    size_t avail = (ws_size > 19136512ULL) ? ws_size - 19136512ULL : 0;
    int W = 2048;                                    // 421 MB total; ws = 1 GiB (round-5 poison)
    while (W > 128 && (size_t)W * 196608ULL > avail) W >>= 1;
    const size_t qkbuf = (size_t)W * 65536;
    bf16* qb = (bf16*)qkv_base;
    bf16* kb = (bf16*)(qkv_base + qkbuf);
    bf16* vb = (bf16*)(qkv_base + 2 * qkbuf);

    convert_w_kernel<<<3072, 256, 0, stream>>>(w_qkv, w_out, Wt, WoT);
    bias_kernel<<<16, 256, 0, stream>>>(rel_log, mlp_w1, mlp_b1, mlp_w2, mlp_b2, bias);
    comb_kernel<<<16384, 256, 0, stream>>>(bias, mask, comb);

    const int nchunk = 2048 / W;
    for (int c = 0; c < nchunk; ++c) {
        const float* xc = x + (size_t)c * W * 64 * 512;
        qkv_fused_kernel<<<W / 2, 512, 0, stream>>>(xc, Wt, qb, kb, vb);
        attn_proj_kernel<<<W, 512, 0, stream>>>(qb, kb, vb, comb, tau, WoT, b_out,
                                                c * W, out + (size_t)c * W * 64 * 512);
    }
}